// Round 1
// 413.284 us; speedup vs baseline: 1.0441x; 1.0441x over previous
//
#include <hip/hip_runtime.h>

#define T 256
#define TC 16            // half-chunk staged in LDS
#define SC 32            // super-chunk: controls load granularity (128 B)
#define NSC (T / SC)     // 8 super-chunks
#define V 64             // vehicles (threads) per block -> SINGLE-WAVE blocks
#define DT 0.05f
#define WHEELBASE 2.7f
#define MAX_STEER 0.5235987755982988f  // deg2rad(30)
#define MAX_SPEED 100.0f
#define FR 0.1f
#define FA 0.01f

// Wave-local LDS fence: orders ds_write -> ds_read across lanes of ONE wave.
// Deliberately does NOT wait vmcnt: global stores from chunk k stay in
// flight and drain under the sim compute of chunk k+1 (no __syncthreads,
// so no compiler-forced "s_waitcnt vmcnt(0)" store drain per chunk).
__device__ __forceinline__ void lds_fence() {
    asm volatile("s_waitcnt lgkmcnt(0)" ::: "memory");
}

// One thread per vehicle, one wave per block (V=64 -> grid=1024 -> 4
// independent blocks/CU that desync naturally, overlapping one block's
// store burst with another's compute phase). States for 16 steps staged in
// double-buffered LDS, then written out transposed so global stores are
// contiguous 64 B per 16 lanes (full sectors, each written exactly once).
__global__ __launch_bounds__(V) void bicycle_kernel(
    const float* __restrict__ sx, const float* __restrict__ sy,
    const float* __restrict__ syaw, const float* __restrict__ ssp,
    const float* __restrict__ accel, const float* __restrict__ steering,
    float* __restrict__ out, int B)
{
    // pad 17: sim-phase write banks (17*tid + j) % 32 -> 2-way (free);
    // writeout read banks (17*(4i+u) + j) % 32 -> max 3-way (~free).
    // Double buffer: writeout reads of buf and next sim writes of buf^1
    // never alias, so the only ordering needed is the lds_fence.
    __shared__ float lds[2][4][V][TC + 1];   // 34,816 B -> 4 blocks/CU

    const int tid = threadIdx.x;
    const int b   = blockIdx.x * V + tid;

    float x   = sx[b];
    float y   = sy[b];
    float yaw = syaw[b];
    float sp  = ssp[b];

    const float4* a4 = (const float4*)(accel    + (size_t)b * T);
    const float4* s4 = (const float4*)(steering + (size_t)b * T);

    const size_t plane   = (size_t)B * T;
    const size_t vehBase = (size_t)blockIdx.x * V;

    const int u = tid >> 4;   // writeout: which vehicle sub-row
    const int j = tid & 15;   // writeout: time offset within half-chunk

    // ---- controls double-buffer in registers; prefetch hides load latency
    // under the previous super-chunk's stores without any vmcnt(0) drain.
    float4 av[SC / 4], sv[SC / 4], avn[SC / 4], svn[SC / 4];
    #pragma unroll
    for (int i = 0; i < SC / 4; ++i) { av[i] = a4[i]; sv[i] = s4[i]; }

    for (int c = 0; c < NSC; ++c) {           // 8 super-chunks of 32 steps
        // prefetch next super-chunk's controls (128 B/thread/array)
        if (c + 1 < NSC) {
            #pragma unroll
            for (int i = 0; i < SC / 4; ++i) {
                avn[i] = a4[(c + 1) * (SC / 4) + i];
                svn[i] = s4[(c + 1) * (SC / 4) + i];
            }
        }

        float ac[SC], scn[SC];
        #pragma unroll
        for (int i = 0; i < SC / 4; ++i) {
            ac[4*i+0]  = av[i].x; ac[4*i+1]  = av[i].y; ac[4*i+2]  = av[i].z; ac[4*i+3]  = av[i].w;
            scn[4*i+0] = sv[i].x; scn[4*i+1] = sv[i].y; scn[4*i+2] = sv[i].z; scn[4*i+3] = sv[i].w;
        }

        #pragma unroll
        for (int h = 0; h < 2; ++h) {         // two half-chunks of 16 steps
            const int buf = h;                // ping-pong (c*2+h parity == h)

            // ---- simulate 16 steps, record pre-step state into LDS
            #pragma unroll
            for (int jj = 0; jj < TC; ++jj) {
                const int t = h * TC + jj;    // compile-time after unroll
                lds[buf][0][tid][jj] = x;
                lds[buf][1][tid][jj] = y;
                lds[buf][2][tid][jj] = yaw;
                lds[buf][3][tid][jj] = sp;

                float fr    = fmaf(FA * sp, sp, sp * FR);
                float spn   = fmaf(DT, ac[t] - fr, sp);
                spn         = fminf(fmaxf(spn, 0.0f), MAX_SPEED);
                float steer = fminf(fmaxf(scn[t], -MAX_STEER), MAX_STEER);
                float angv  = sp * __tanf(steer) * (1.0f / WHEELBASE);
                float s_, c_;
                __sincosf(yaw, &s_, &c_);
                float spDT = sp * DT;
                x   = fmaf(spDT, c_, x);
                y   = fmaf(spDT, s_, y);
                yaw = fmaf(angv, DT, yaw);
                sp  = spn;
            }

            lds_fence();   // ds_writes visible wave-wide; stores NOT drained

            // ---- cooperative transposed writeout (single wave):
            // lanes (u, j): vehicle vv = i*4+u, time j. 16 consecutive lanes
            // write 64 B contiguous; stores overlap the next sim phase.
            const int t0 = c * SC + h * TC;
            #pragma unroll
            for (int p = 0; p < 4; ++p) {
                float* op = out + (size_t)p * plane + vehBase * T + t0;
                #pragma unroll
                for (int i = 0; i < TC; ++i) {
                    const int vv = i * 4 + u;
                    __builtin_nontemporal_store(lds[buf][p][vv][j],
                                                &op[(size_t)vv * T + j]);
                }
            }
            // no trailing barrier: double buffer + next lds_fence's
            // lgkmcnt(0) cover the read-before-overwrite hazard.
        }

        if (c + 1 < NSC) {
            #pragma unroll
            for (int i = 0; i < SC / 4; ++i) { av[i] = avn[i]; sv[i] = svn[i]; }
        }
    }
}

extern "C" void kernel_launch(void* const* d_in, const int* in_sizes, int n_in,
                              void* d_out, int out_size, void* d_ws, size_t ws_size,
                              hipStream_t stream) {
    const float* sx       = (const float*)d_in[0];
    const float* sy       = (const float*)d_in[1];
    const float* syaw     = (const float*)d_in[2];
    const float* ssp      = (const float*)d_in[3];
    const float* steering = (const float*)d_in[5];
    const float* accel    = (const float*)d_in[4];
    float* out = (float*)d_out;

    int B = in_sizes[0];
    dim3 block(V);
    dim3 grid(B / V);
    hipLaunchKernelGGL(bicycle_kernel, grid, block, 0, stream,
                       sx, sy, syaw, ssp, accel, steering, out, B);
}